// Round 8
// baseline (144.433 us; speedup 1.0000x reference)
//
#include <hip/hip_runtime.h>
#include <math.h>

#define BH  16384   // half batch
#define B2  32768
#define DIM 256
#define KC  1024    // clusters

typedef __bf16 bf16x8 __attribute__((ext_vector_type(8)));
typedef float  f32x4  __attribute__((ext_vector_type(4)));

#define S_SCL  6.35f
#define S_INV  (1.0f / 6.35f)

__device__ __forceinline__ unsigned short f2bf(float f) {
  unsigned int u = __float_as_uint(f);
  u += 0x7FFFu + ((u >> 16) & 1u);   // RNE; inputs are finite
  return (unsigned short)(u >> 16);
}

__device__ __forceinline__ float vsqrt(float x) {
  float r; asm("v_sqrt_f32 %0, %1" : "=v"(r) : "v"(x)); return r;
}

__device__ __forceinline__ float dist_L(float dotv) {
  // L = D/eps = 20*sqrt(max(2-2*dot, 1e-12))
  return 20.0f * vsqrt(fmaxf(2.0f - 2.0f * dotv, 1e-12f));
}

__device__ __forceinline__ void gld_lds16(const void* g, void* l) {
  __builtin_amdgcn_global_load_lds(
      (const __attribute__((address_space(1))) void*)g,
      (__attribute__((address_space(3))) void*)l, 16, 0, 0);
}

// one wave per row: l2-normalize and convert to bf16.
// Blocks 0..15 also zero colsum; block 16 zeros out.
__global__ void norm_rows_kernel(const float* __restrict__ z,
                                 const float* __restrict__ p,
                                 const float* __restrict__ c,
                                 unsigned short* __restrict__ Xn,
                                 unsigned short* __restrict__ Cn,
                                 float* __restrict__ colsum,
                                 float* __restrict__ out) {
  if (blockIdx.x < 16) colsum[blockIdx.x * 256 + threadIdx.x] = 0.0f;
  if (blockIdx.x == 16 && threadIdx.x == 0) out[0] = 0.0f;

  int wave = threadIdx.x >> 6;
  int lane = threadIdx.x & 63;
  int row  = blockIdx.x * 4 + wave;          // 0 .. 66559
  const float* src; unsigned short* dst; int r;
  if (row < B2)        { src = z; dst = Xn; r = row; }
  else if (row < 2*B2) { src = p; dst = Xn + (size_t)B2 * DIM; r = row - B2; }
  else                 { src = c; dst = Cn; r = row - 2*B2; }
  float4 v = *reinterpret_cast<const float4*>(src + (size_t)r * DIM + lane * 4);
  float ss = v.x*v.x + v.y*v.y + v.z*v.z + v.w*v.w;
  #pragma unroll
  for (int m = 1; m < 64; m <<= 1) ss += __shfl_xor(ss, m);
  float inv = 1.0f / fmaxf(vsqrt(ss), 1e-12f);
  ushort4 o;
  o.x = f2bf(v.x * inv); o.y = f2bf(v.y * inv);
  o.z = f2bf(v.z * inv); o.w = f2bf(v.w * inv);
  *reinterpret_cast<ushort4*>(dst + (size_t)r * DIM + lane * 4) = o;
}

__global__ void fin_logC_kernel(const float* __restrict__ colsum,
                                float* __restrict__ logC) {
  int i = blockIdx.x * 256 + threadIdx.x;
  if (i < 4 * KC) logC[i] = 40.0f + __logf(colsum[i]);
}

// gemm_s: colsum[mat][k] += sum_b exp(L-40)  AND  S[mat][b][k] = u8(L*6.35)
__global__ __launch_bounds__(256, 2)
void gemm_s_kernel(const unsigned short* __restrict__ XA,  // [4][BH][DIM]
                   const unsigned short* __restrict__ Cn,  // [KC][DIM]
                   float* __restrict__ colsum,
                   unsigned char* __restrict__ S) {        // [4][BH][KC] u8
  __shared__ __align__(16) char lds[65536];  // A: 2x16KB @0; B: 2x16KB @32768
  const int id  = blockIdx.x;            // 1024
  const int xcd = id & 7, idx = id >> 3;
  const int wk  = xcd * 128 + idx;       // bijective (1024 % 8 == 0)
  const int panel = wk >> 3, col = wk & 7;
  const int tm0 = panel * 128, tn0 = col * 128;

  const int tid  = threadIdx.x;
  const int lane = tid & 63;
  const int wid  = tid >> 6;
  const int wm   = wid >> 1, wn = wid & 1;
  const int l15  = lane & 15, l4 = lane >> 4;

  int arow[4], acs[4];
  #pragma unroll
  for (int it = 0; it < 4; ++it) {
    int slot = it * 256 + tid;
    int r = slot >> 3, c = slot & 7;
    arow[it] = r;
    acs[it]  = c ^ (r & 7);    // pre-swizzled source chunk (involution)
  }
  const char* Abase = (const char*)XA + (size_t)tm0 * 512;
  const char* Bbase = (const char*)Cn + (size_t)tn0 * 512;

  auto stage = [&](int t) {
    const int mat = t >> 2;
    const int bk  = t & 3;
    const int b   = t & 1;
    const char* ab = Abase + ((size_t)mat << 23);   // mat * BH * 512
    #pragma unroll
    for (int it = 0; it < 4; ++it) {
      gld_lds16(ab + (size_t)arow[it] * 512 + bk * 128 + acs[it] * 16,
                lds + b * 16384 + (it * 256 + tid) * 16);
      gld_lds16(Bbase + (size_t)arow[it] * 512 + bk * 128 + acs[it] * 16,
                lds + 32768 + b * 16384 + (it * 256 + tid) * 16);
    }
  };

  f32x4 acc[4][4];
  stage(0);
  __syncthreads();

  for (int t = 0; t < 16; ++t) {
    if (t < 15) stage(t + 1);
    const int b  = t & 1;
    const int mat = t >> 2, bk = t & 3;

    if (bk == 0) {
      #pragma unroll
      for (int fi = 0; fi < 4; ++fi)
        #pragma unroll
        for (int fj = 0; fj < 4; ++fj)
          acc[fi][fj] = (f32x4){0.f, 0.f, 0.f, 0.f};
    }

    #pragma unroll
    for (int kc = 0; kc < 2; ++kc) {
      bf16x8 aF[4], bF[4];
      #pragma unroll
      for (int f = 0; f < 4; ++f) {
        const int ra = wm * 64 + f * 16 + l15;
        aF[f] = *reinterpret_cast<const bf16x8*>(
            lds + b * 16384 + ra * 128 + ((((kc << 2) | l4) ^ (ra & 7)) << 4));
        const int rb = wn * 64 + f * 16 + l15;
        bF[f] = *reinterpret_cast<const bf16x8*>(
            lds + 32768 + b * 16384 + rb * 128 + ((((kc << 2) | l4) ^ (rb & 7)) << 4));
      }
      #pragma unroll
      for (int fi = 0; fi < 4; ++fi)
        #pragma unroll
        for (int fj = 0; fj < 4; ++fj)
          acc[fi][fj] = __builtin_amdgcn_mfma_f32_16x16x32_bf16(
              aF[fi], bF[fj], acc[fi][fj], 0, 0, 0);
    }

    if (bk == 3) {
      unsigned char* Sp = S + ((size_t)mat * BH + tm0) * KC + tn0;
      #pragma unroll
      for (int fj = 0; fj < 4; ++fj) {
        float cp = 0.0f;
        #pragma unroll
        for (int fi = 0; fi < 4; ++fi)
          #pragma unroll
          for (int i = 0; i < 4; ++i) {
            float L = dist_L(acc[fi][fj][i]);
            cp += __expf(L - 40.0f);
            unsigned e = (unsigned)fminf(L * S_SCL + 0.5f, 255.0f);
            int row  = wm * 64 + fi * 16 + l4 * 4 + i;
            int ccol = wn * 64 + fj * 16 + l15;
            Sp[(size_t)row * KC + ccol] = (unsigned char)e;
          }
        cp += __shfl_xor(cp, 16);
        cp += __shfl_xor(cp, 32);
        if (l4 == 0)
          atomicAdd(&colsum[mat * KC + tn0 + wn * 64 + fj * 16 + l15], cp);
      }
    }
    __syncthreads();
  }
}

__device__ __forceinline__ void dec4(unsigned w, const float* lc, float* g) {
  g[0] = (float)(w & 0xffu)         * S_INV - lc[0];
  g[1] = (float)((w >> 8) & 0xffu)  * S_INV - lc[1];
  g[2] = (float)((w >> 16) & 0xffu) * S_INV - lc[2];
  g[3] = (float)(w >> 24)           * S_INV - lc[3];
}

// one wave per row: stream 4 planes of S (u8), accumulate per-row loss,
// block-reduce, one atomic per block.
__global__ __launch_bounds__(256)
void pass2_mem_kernel(const unsigned char* __restrict__ S,
                      const float* __restrict__ logC,
                      float* __restrict__ out) {
  const int tid  = threadIdx.x;
  const int lane = tid & 63;
  const int wid  = tid >> 6;
  const int row  = blockIdx.x * 4 + wid;      // 4096 blocks -> BH rows
  const size_t plane = (size_t)BH * KC;
  const unsigned char* Sr = S + (size_t)row * KC;

  float dp1 = 0.f, dp2 = 0.f, dz1 = 0.f, dz2 = 0.f, nz1 = 0.f, nz2 = 0.f;

  #pragma unroll
  for (int it = 0; it < 2; ++it) {
    const int kb = it * 512 + lane * 8;
    uint2 vz1 = *reinterpret_cast<const uint2*>(Sr + 0 * plane + kb);
    uint2 vz2 = *reinterpret_cast<const uint2*>(Sr + 1 * plane + kb);
    uint2 vp1 = *reinterpret_cast<const uint2*>(Sr + 2 * plane + kb);
    uint2 vp2 = *reinterpret_cast<const uint2*>(Sr + 3 * plane + kb);

    float cz1[8], cz2[8], cp1[8], cp2[8];
    *reinterpret_cast<float4*>(&cz1[0]) = *reinterpret_cast<const float4*>(logC + 0 * KC + kb);
    *reinterpret_cast<float4*>(&cz1[4]) = *reinterpret_cast<const float4*>(logC + 0 * KC + kb + 4);
    *reinterpret_cast<float4*>(&cz2[0]) = *reinterpret_cast<const float4*>(logC + 1 * KC + kb);
    *reinterpret_cast<float4*>(&cz2[4]) = *reinterpret_cast<const float4*>(logC + 1 * KC + kb + 4);
    *reinterpret_cast<float4*>(&cp1[0]) = *reinterpret_cast<const float4*>(logC + 2 * KC + kb);
    *reinterpret_cast<float4*>(&cp1[4]) = *reinterpret_cast<const float4*>(logC + 2 * KC + kb + 4);
    *reinterpret_cast<float4*>(&cp2[0]) = *reinterpret_cast<const float4*>(logC + 3 * KC + kb);
    *reinterpret_cast<float4*>(&cp2[4]) = *reinterpret_cast<const float4*>(logC + 3 * KC + kb + 4);

    float g1[8], g2[8], tv[8];
    // p1 / p2
    dec4(vp1.x, &cp1[0], &g1[0]); dec4(vp1.y, &cp1[4], &g1[4]);
    dec4(vp2.x, &cp2[0], &g2[0]); dec4(vp2.y, &cp2[4], &g2[4]);
    #pragma unroll
    for (int e = 0; e < 8; ++e) {
      dp1 += __expf(g1[e]);
      dp2 += __expf(g2[e]);
      tv[e] = g1[e] + g2[e];
    }
    // z1 / z2
    dec4(vz1.x, &cz1[0], &g1[0]); dec4(vz1.y, &cz1[4], &g1[4]);
    dec4(vz2.x, &cz2[0], &g2[0]); dec4(vz2.y, &cz2[4], &g2[4]);
    #pragma unroll
    for (int e = 0; e < 8; ++e) {
      float e1 = __expf(g1[e]);
      float e2 = __expf(g2[e]);
      dz1 += e1; nz1 += e1 * tv[e];
      dz2 += e2; nz2 += e2 * tv[e];
    }
  }

  #pragma unroll
  for (int m = 1; m < 64; m <<= 1) {
    dp1 += __shfl_xor(dp1, m); dp2 += __shfl_xor(dp2, m);
    dz1 += __shfl_xor(dz1, m); dz2 += __shfl_xor(dz2, m);
    nz1 += __shfl_xor(nz1, m); nz2 += __shfl_xor(nz2, m);
  }

  __shared__ float red[4];
  if (lane == 0)
    red[wid] = nz1 / dz1 + nz2 / dz2 - 2.0f * (__logf(dp1) + __logf(dp2));
  __syncthreads();
  if (tid == 0)
    atomicAdd(out, (red[0] + red[1] + red[2] + red[3]) * (-1.0f / 65536.0f));
}

extern "C" void kernel_launch(void* const* d_in, const int* in_sizes, int n_in,
                              void* d_out, int out_size, void* d_ws, size_t ws_size,
                              hipStream_t stream) {
  const float* z = (const float*)d_in[0];
  const float* p = (const float*)d_in[1];
  const float* c = (const float*)d_in[2];
  char* ws = (char*)d_ws;
  // layout: XA bf16 33.55MB | Cn 0.5MB | colsum 16KB | logC 16KB | S u8 67.1MB
  unsigned short* Xn = (unsigned short*)(ws);
  unsigned short* Cn = (unsigned short*)(ws + 33554432);
  float* colsum = (float*)(ws + 34078720);
  float* logC   = (float*)(ws + 34095104);
  unsigned char* S = (unsigned char*)(ws + 34111488);
  float* out = (float*)d_out;

  norm_rows_kernel<<<16640, 256, 0, stream>>>(z, p, c, Xn, Cn, colsum, out);
  gemm_s_kernel<<<1024, 256, 0, stream>>>(Xn, Cn, colsum, S);
  fin_logC_kernel<<<16, 256, 0, stream>>>(colsum, logC);
  pass2_mem_kernel<<<4096, 256, 0, stream>>>(S, logC, out);
}

// Round 9
// 107.754 us; speedup vs baseline: 1.3404x; 1.3404x over previous
//
#include <hip/hip_runtime.h>
#include <math.h>

#define BH  16384   // half batch
#define B2  32768
#define DIM 256
#define KC  1024    // clusters

typedef __bf16 bf16x8 __attribute__((ext_vector_type(8)));
typedef float  f32x4  __attribute__((ext_vector_type(4)));

__device__ __forceinline__ unsigned short f2bf(float f) {
  unsigned int u = __float_as_uint(f);
  u += 0x7FFFu + ((u >> 16) & 1u);   // RNE; inputs are finite
  return (unsigned short)(u >> 16);
}

__device__ __forceinline__ float vsqrt(float x) {
  float r; asm("v_sqrt_f32 %0, %1" : "=v"(r) : "v"(x)); return r;
}

__device__ __forceinline__ void gld_lds16(const void* g, void* l) {
  __builtin_amdgcn_global_load_lds(
      (const __attribute__((address_space(1))) void*)g,
      (__attribute__((address_space(3))) void*)l, 16, 0, 0);
}

// one wave per row: l2-normalize and convert to bf16.
// Blocks 0..15 also zero colsum; block 16 zeros out.
__global__ void norm_rows_kernel(const float* __restrict__ z,
                                 const float* __restrict__ p,
                                 const float* __restrict__ c,
                                 unsigned short* __restrict__ Xn,
                                 unsigned short* __restrict__ Cn,
                                 float* __restrict__ colsum,
                                 float* __restrict__ out) {
  if (blockIdx.x < 16) colsum[blockIdx.x * 256 + threadIdx.x] = 0.0f;
  if (blockIdx.x == 16 && threadIdx.x == 0) out[0] = 0.0f;

  int wave = threadIdx.x >> 6;
  int lane = threadIdx.x & 63;
  int row  = blockIdx.x * 4 + wave;          // 0 .. 66559
  const float* src; unsigned short* dst; int r;
  if (row < B2)        { src = z; dst = Xn; r = row; }
  else if (row < 2*B2) { src = p; dst = Xn + (size_t)B2 * DIM; r = row - B2; }
  else                 { src = c; dst = Cn; r = row - 2*B2; }
  float4 v = *reinterpret_cast<const float4*>(src + (size_t)r * DIM + lane * 4);
  float ss = v.x*v.x + v.y*v.y + v.z*v.z + v.w*v.w;
  #pragma unroll
  for (int m = 1; m < 64; m <<= 1) ss += __shfl_xor(ss, m);
  float inv = 1.0f / fmaxf(vsqrt(ss), 1e-12f);
  ushort4 o;
  o.x = f2bf(v.x * inv); o.y = f2bf(v.y * inv);
  o.z = f2bf(v.z * inv); o.w = f2bf(v.w * inv);
  *reinterpret_cast<ushort4*>(dst + (size_t)r * DIM + lane * 4) = o;
}

__global__ void fin_logC_kernel(const float* __restrict__ colsum,
                                float* __restrict__ logC) {
  int i = blockIdx.x * 256 + threadIdx.x;
  if (i < 4 * KC) logC[i] = 40.0f + __logf(colsum[i]);
}

// gemm_s: S[mat][b][k] = u8 quantized dot; colsum[mat][k] += LUT[e]
// e = floor(d*255 + 128), d_e = (e-127.5)/255, LUT[e] = exp(L(d_e)-40)
__global__ __launch_bounds__(256, 2)
void gemm_s_kernel(const unsigned short* __restrict__ XA,  // [4][BH][DIM]
                   const unsigned short* __restrict__ Cn,  // [KC][DIM]
                   float* __restrict__ colsum,
                   unsigned char* __restrict__ S) {        // [4][BH][KC] u8
  __shared__ __align__(16) char lds[65536 + 4096];  // tiles + 256x4 f32 LUT
  float* lut4 = (float*)(lds + 65536);
  const int id  = blockIdx.x;            // 1024
  const int xcd = id & 7, idx = id >> 3;
  const int wk  = xcd * 128 + idx;       // bijective (1024 % 8 == 0)
  const int panel = wk >> 3, col = wk & 7;
  const int tm0 = panel * 128, tn0 = col * 128;

  const int tid  = threadIdx.x;
  const int lane = tid & 63;
  const int wid  = tid >> 6;
  const int wm   = wid >> 1, wn = wid & 1;
  const int l15  = lane & 15, l4 = lane >> 4;
  const int slot = tid & 3;

  int arow[4], acs[4];
  #pragma unroll
  for (int it = 0; it < 4; ++it) {
    int sl = it * 256 + tid;
    int r = sl >> 3, c = sl & 7;
    arow[it] = r;
    acs[it]  = c ^ (r & 7);    // pre-swizzled source chunk (involution)
  }
  const char* Abase = (const char*)XA + (size_t)tm0 * 512;
  const char* Bbase = (const char*)Cn + (size_t)tn0 * 512;

  auto stage = [&](int t) {
    const int mat = t >> 2;
    const int bk  = t & 3;
    const int b   = t & 1;
    const char* ab = Abase + ((size_t)mat << 23);   // mat * BH * 512
    #pragma unroll
    for (int it = 0; it < 4; ++it) {
      gld_lds16(ab + (size_t)arow[it] * 512 + bk * 128 + acs[it] * 16,
                lds + b * 16384 + (it * 256 + tid) * 16);
      gld_lds16(Bbase + (size_t)arow[it] * 512 + bk * 128 + acs[it] * 16,
                lds + 32768 + b * 16384 + (it * 256 + tid) * 16);
    }
  };

  // build LUT (before the barrier that precedes first compute)
  if (tid < 256) {
    float d = ((float)tid - 127.5f) * (1.0f / 255.0f);
    float L = 20.0f * vsqrt(2.0f - 2.0f * d);
    float v = __expf(L - 40.0f);
    ((float4*)lut4)[tid] = (float4){v, v, v, v};
  }

  f32x4 acc[4][4];
  stage(0);
  __syncthreads();

  for (int t = 0; t < 16; ++t) {
    if (t < 15) stage(t + 1);
    const int b  = t & 1;
    const int mat = t >> 2, bk = t & 3;

    if (bk == 0) {
      #pragma unroll
      for (int fi = 0; fi < 4; ++fi)
        #pragma unroll
        for (int fj = 0; fj < 4; ++fj)
          acc[fi][fj] = (f32x4){0.f, 0.f, 0.f, 0.f};
    }

    #pragma unroll
    for (int kc = 0; kc < 2; ++kc) {
      bf16x8 aF[4], bF[4];
      #pragma unroll
      for (int f = 0; f < 4; ++f) {
        const int ra = wm * 64 + f * 16 + l15;
        aF[f] = *reinterpret_cast<const bf16x8*>(
            lds + b * 16384 + ra * 128 + ((((kc << 2) | l4) ^ (ra & 7)) << 4));
        const int rb = wn * 64 + f * 16 + l15;
        bF[f] = *reinterpret_cast<const bf16x8*>(
            lds + 32768 + b * 16384 + rb * 128 + ((((kc << 2) | l4) ^ (rb & 7)) << 4));
      }
      #pragma unroll
      for (int fi = 0; fi < 4; ++fi)
        #pragma unroll
        for (int fj = 0; fj < 4; ++fj)
          acc[fi][fj] = __builtin_amdgcn_mfma_f32_16x16x32_bf16(
              aF[fi], bF[fj], acc[fi][fj], 0, 0, 0);
    }

    if (bk == 3) {
      unsigned char* Sp = S + ((size_t)mat * BH + tm0) * KC + tn0;
      #pragma unroll
      for (int fj = 0; fj < 4; ++fj) {
        float cp = 0.0f;
        #pragma unroll
        for (int fi = 0; fi < 4; ++fi)
          #pragma unroll
          for (int i = 0; i < 4; ++i) {
            float v = fmaf(acc[fi][fj][i], 255.0f, 128.0f);
            v = fminf(fmaxf(v, 0.0f), 255.0f);
            unsigned e = (unsigned)v;
            cp += lut4[(e << 2) | slot];
            int row  = wm * 64 + fi * 16 + l4 * 4 + i;
            int ccol = wn * 64 + fj * 16 + l15;
            Sp[(size_t)row * KC + ccol] = (unsigned char)e;
          }
        cp += __shfl_xor(cp, 16);
        cp += __shfl_xor(cp, 32);
        if (l4 == 0)
          atomicAdd(&colsum[mat * KC + tn0 + wn * 64 + fj * 16 + l15], cp);
      }
    }
    __syncthreads();
  }
}

// decode u8 -> G = L(d_e) - lc
__device__ __forceinline__ float decG(unsigned e, float lc) {
  float d = fmaf((float)e, 1.0f / 255.0f, -0.5f);
  float L = 20.0f * vsqrt(fmaf(-2.0f, d, 2.0f));
  return L - lc;
}

// one wave per row: stream 4 planes of S (u8), per-row loss; one global
// write per block (no hot atomics).
__global__ __launch_bounds__(256)
void pass2_mem_kernel(const unsigned char* __restrict__ S,
                      const float* __restrict__ logC,
                      float* __restrict__ rowv) {
  const int tid  = threadIdx.x;
  const int lane = tid & 63;
  const int wid  = tid >> 6;
  const int row  = blockIdx.x * 4 + wid;      // 4096 blocks -> BH rows
  const size_t plane = (size_t)BH * KC;
  const unsigned char* Sr = S + (size_t)row * KC;

  float dp1 = 0.f, dp2 = 0.f, dz1 = 0.f, dz2 = 0.f, nz1 = 0.f, nz2 = 0.f;

  #pragma unroll
  for (int it = 0; it < 2; ++it) {
    const int kb = it * 512 + lane * 8;
    uint2 vz1 = *reinterpret_cast<const uint2*>(Sr + 0 * plane + kb);
    uint2 vz2 = *reinterpret_cast<const uint2*>(Sr + 1 * plane + kb);
    uint2 vp1 = *reinterpret_cast<const uint2*>(Sr + 2 * plane + kb);
    uint2 vp2 = *reinterpret_cast<const uint2*>(Sr + 3 * plane + kb);

    float cz1[8], cz2[8], cp1[8], cp2[8];
    *reinterpret_cast<float4*>(&cz1[0]) = *reinterpret_cast<const float4*>(logC + 0 * KC + kb);
    *reinterpret_cast<float4*>(&cz1[4]) = *reinterpret_cast<const float4*>(logC + 0 * KC + kb + 4);
    *reinterpret_cast<float4*>(&cz2[0]) = *reinterpret_cast<const float4*>(logC + 1 * KC + kb);
    *reinterpret_cast<float4*>(&cz2[4]) = *reinterpret_cast<const float4*>(logC + 1 * KC + kb + 4);
    *reinterpret_cast<float4*>(&cp1[0]) = *reinterpret_cast<const float4*>(logC + 2 * KC + kb);
    *reinterpret_cast<float4*>(&cp1[4]) = *reinterpret_cast<const float4*>(logC + 2 * KC + kb + 4);
    *reinterpret_cast<float4*>(&cp2[0]) = *reinterpret_cast<const float4*>(logC + 3 * KC + kb);
    *reinterpret_cast<float4*>(&cp2[4]) = *reinterpret_cast<const float4*>(logC + 3 * KC + kb + 4);

    unsigned b1[8], b2[8];
    #pragma unroll
    for (int e = 0; e < 4; ++e) {
      b1[e]     = (vp1.x >> (8 * e)) & 0xffu;
      b1[e + 4] = (vp1.y >> (8 * e)) & 0xffu;
      b2[e]     = (vp2.x >> (8 * e)) & 0xffu;
      b2[e + 4] = (vp2.y >> (8 * e)) & 0xffu;
    }
    float tv[8];
    #pragma unroll
    for (int e = 0; e < 8; ++e) {
      float g1 = decG(b1[e], cp1[e]);
      float g2 = decG(b2[e], cp2[e]);
      dp1 += __expf(g1);
      dp2 += __expf(g2);
      tv[e] = g1 + g2;
    }
    #pragma unroll
    for (int e = 0; e < 4; ++e) {
      b1[e]     = (vz1.x >> (8 * e)) & 0xffu;
      b1[e + 4] = (vz1.y >> (8 * e)) & 0xffu;
      b2[e]     = (vz2.x >> (8 * e)) & 0xffu;
      b2[e + 4] = (vz2.y >> (8 * e)) & 0xffu;
    }
    #pragma unroll
    for (int e = 0; e < 8; ++e) {
      float e1 = __expf(decG(b1[e], cz1[e]));
      float e2 = __expf(decG(b2[e], cz2[e]));
      dz1 += e1; nz1 += e1 * tv[e];
      dz2 += e2; nz2 += e2 * tv[e];
    }
  }

  #pragma unroll
  for (int m = 1; m < 64; m <<= 1) {
    dp1 += __shfl_xor(dp1, m); dp2 += __shfl_xor(dp2, m);
    dz1 += __shfl_xor(dz1, m); dz2 += __shfl_xor(dz2, m);
    nz1 += __shfl_xor(nz1, m); nz2 += __shfl_xor(nz2, m);
  }

  __shared__ float red[4];
  if (lane == 0)
    red[wid] = nz1 / dz1 + nz2 / dz2 - 2.0f * (__logf(dp1) + __logf(dp2));
  __syncthreads();
  if (tid == 0)
    rowv[blockIdx.x] = red[0] + red[1] + red[2] + red[3];
}

// 4096 partials -> 16 blocks -> 16 atomics
__global__ void fin_reduce_kernel(const float* __restrict__ rowv,
                                  float* __restrict__ out) {
  int i = blockIdx.x * 256 + threadIdx.x;
  float v = rowv[i];
  #pragma unroll
  for (int m = 1; m < 64; m <<= 1) v += __shfl_xor(v, m);
  __shared__ float ws[4];
  int lane = threadIdx.x & 63, wid = threadIdx.x >> 6;
  if (lane == 0) ws[wid] = v;
  __syncthreads();
  if (threadIdx.x == 0)
    atomicAdd(out, (ws[0] + ws[1] + ws[2] + ws[3]) * (-1.0f / 65536.0f));
}

extern "C" void kernel_launch(void* const* d_in, const int* in_sizes, int n_in,
                              void* d_out, int out_size, void* d_ws, size_t ws_size,
                              hipStream_t stream) {
  const float* z = (const float*)d_in[0];
  const float* p = (const float*)d_in[1];
  const float* c = (const float*)d_in[2];
  char* ws = (char*)d_ws;
  // layout: XA bf16 33.55MB | Cn 0.5MB | colsum 16KB | logC 16KB |
  //         rowv 16KB | S u8 67.1MB
  unsigned short* Xn = (unsigned short*)(ws);
  unsigned short* Cn = (unsigned short*)(ws + 33554432);
  float* colsum = (float*)(ws + 34078720);
  float* logC   = (float*)(ws + 34095104);
  float* rowv   = (float*)(ws + 34111488);
  unsigned char* S = (unsigned char*)(ws + 34127872);
  float* out = (float*)d_out;

  norm_rows_kernel<<<16640, 256, 0, stream>>>(z, p, c, Xn, Cn, colsum, out);
  gemm_s_kernel<<<1024, 256, 0, stream>>>(Xn, Cn, colsum, S);
  fin_logC_kernel<<<16, 256, 0, stream>>>(colsum, logC);
  pass2_mem_kernel<<<4096, 256, 0, stream>>>(S, logC, rowv);
  fin_reduce_kernel<<<16, 256, 0, stream>>>(rowv, out);
}